// Round 10
// baseline (243.703 us; speedup 1.0000x reference)
//
#include <hip/hip_runtime.h>

#define BD 8
#define SD 64
#define CD 3
#define HD 224
#define WD 224
#define ED 128
#define PD 16
#define HWD (HD*WD)
#define KD (CD*PD*PD)   /* 768 */

// All buffers fp32 (confirmed R6+ passes). Scratch in module globals.
// R9 post-mortem: global fp32 atomicAdd scatter = 30 MB of line-grain HBM RMW
// traffic at 457 GB/s ~= the whole 82 us. Restructured scatter->gather: no
// global atomics anywhere, no zero-init pass.
__device__ float g_buf[BD * SD * KD];   // [B][S][C][256] f32 (fully overwritten)
__device__ int   g_labels[BD * HWD];    // per-pixel argmax label
__device__ int   g_cnt[BD * SD];        // presence flag per (b,label)

// Kernel 1: 3x3 SAME conv -> argmax(64ch) -> labels store. R7-proven conv path.
__global__ __launch_bounds__(256) void k_labels(
    const float* __restrict__ img,
    const float* __restrict__ wsp,
    const float* __restrict__ bsp)
{
    const int w = blockIdx.x * 64 + threadIdx.x;
    const int h = blockIdx.y * 4 + threadIdx.y;
    const int b = blockIdx.z;
    if (w >= WD) return;

    const float* ib = img + (size_t)b * CD * HWD;
    float pix[27];
    #pragma unroll
    for (int c = 0; c < 3; ++c)
        #pragma unroll
        for (int dh = 0; dh < 3; ++dh)
            #pragma unroll
            for (int dw = 0; dw < 3; ++dw) {
                int hh = h + dh - 1, ww = w + dw - 1;
                bool ok = (hh >= 0) & (hh < HD) & (ww >= 0) & (ww < WD);
                pix[(c * 3 + dh) * 3 + dw] = ok ? ib[c * HWD + hh * WD + ww] : 0.f;
            }

    float best = -INFINITY;
    int bi = 0;
    for (int s = 0; s < SD; ++s) {
        const float* wr = wsp + s * 27;        // wave-uniform -> s_load
        float acc = bsp[s];
        #pragma unroll
        for (int j = 0; j < 27; ++j) acc = fmaf(pix[j], wr[j], acc);
        if (acc > best) { best = acc; bi = s; }   // strict > = first max (jnp.argmax)
    }
    g_labels[b * HWD + h * WD + w] = bi;
}

// Kernel 2: gather per (b,label): scan labels, accumulate matching pixels into
// a 3KB LDS table, then exclusively own g_buf[b][l] (plain store) + presence.
__global__ __launch_bounds__(256) void k_gather(const float* __restrict__ img)
{
    const int l = blockIdx.x;
    const int b = blockIdx.y;
    const int tid = threadIdx.x;

    __shared__ float acc[KD];      // [3][256]
    __shared__ int anyflag;
    ((float4*)acc)[tid] = make_float4(0.f, 0.f, 0.f, 0.f);   // 256*16B = 4KB... KD*4 = 3KB
    if (tid == 0) anyflag = 0;
    __syncthreads();

    const int*   lb = g_labels + (size_t)b * HWD;
    const float* ib = img + (size_t)b * CD * HWD;

    bool found = false;
    for (int base = 0; base < HWD; base += 1024) {   // 50176 = 49*1024 exact
        #pragma unroll
        for (int k = 0; k < 4; ++k) {
            const int p = base + k * 256 + tid;
            const int lab = lb[p];                   // 4 independent coalesced loads
            if (lab == l) {
                found = true;
                const int h = p / WD, w = p - h * WD;
                const int cell = ((h & 15) << 4) | (w & 15);
                atomicAdd(&acc[cell],       ib[p]);
                atomicAdd(&acc[cell + 256], ib[p + HWD]);
                atomicAdd(&acc[cell + 512], ib[p + 2 * HWD]);
            }
        }
    }
    if (found) anyflag = 1;        // benign race: all writers store 1
    __syncthreads();

    float* gr = g_buf + (size_t)(b * SD + l) * KD;
    #pragma unroll
    for (int k = tid; k < KD; k += 256) gr[k] = acc[k];
    if (tid == 0) g_cnt[b * SD + l] = anyflag;
}

// Kernel 3: out[b,i,e] = bias[e] + (1/196)*dot(g_buf[b,uniq(b,i),:], wp[e,:]).
// uniq(b,i) = i-th set bit of the presence mask (ballot over g_cnt), 0-padded.
// Layout: lane = k-dim (coalesced wp/g reads), wave owns 32 e's, shfl reduce.
__global__ __launch_bounds__(256) void k_out(
    const float* __restrict__ wp,
    const float* __restrict__ bp,
    float* __restrict__ out)
{
    const int i = blockIdx.x;
    const int b = blockIdx.y;
    const int lane = threadIdx.x & 63;
    const int wv = threadIdx.x >> 6;

    unsigned long long m = __ballot(g_cnt[b * SD + lane] != 0);
    int l = 0;
    if (i < __popcll(m)) {
        unsigned long long mm = m;
        for (int t = 0; t < i; ++t) mm &= mm - 1;   // clear i lowest set bits
        l = __builtin_ctzll(mm);                    // i-th smallest label (sorted unique)
    }

    const float4* gr = (const float4*)(g_buf + (size_t)(b * SD + l) * KD);
    const float4 g0 = gr[lane], g1 = gr[lane + 64], g2 = gr[lane + 128];

    #pragma unroll 4
    for (int j = 0; j < 32; ++j) {
        const int e = wv * 32 + j;
        const float4* wr = (const float4*)(wp + (size_t)e * KD);
        float4 a0 = wr[lane], a1 = wr[lane + 64], a2 = wr[lane + 128];  // coalesced 1KB/wave
        float acc = g0.x * a0.x;
        acc = fmaf(g0.y, a0.y, acc); acc = fmaf(g0.z, a0.z, acc); acc = fmaf(g0.w, a0.w, acc);
        acc = fmaf(g1.x, a1.x, acc); acc = fmaf(g1.y, a1.y, acc);
        acc = fmaf(g1.z, a1.z, acc); acc = fmaf(g1.w, a1.w, acc);
        acc = fmaf(g2.x, a2.x, acc); acc = fmaf(g2.y, a2.y, acc);
        acc = fmaf(g2.z, a2.z, acc); acc = fmaf(g2.w, a2.w, acc);
        #pragma unroll
        for (int off = 32; off; off >>= 1) acc += __shfl_xor(acc, off, 64);
        if (lane == 0)
            out[(size_t)(b * SD + i) * ED + e] = bp[e] + acc * (1.f / 196.f);
    }
}

extern "C" void kernel_launch(void* const* d_in, const int* in_sizes, int n_in,
                              void* d_out, int out_size, void* d_ws, size_t ws_size,
                              hipStream_t stream) {
    const float *img = nullptr, *wsp = nullptr, *bsp = nullptr, *wp = nullptr, *bp = nullptr;
    for (int i = 0; i < n_in; ++i) {
        switch (in_sizes[i]) {
            case BD * CD * HWD:      img = (const float*)d_in[i]; break;  // 1204224
            case SD * CD * 9:        wsp = (const float*)d_in[i]; break;  // 1728
            case SD:                 bsp = (const float*)d_in[i]; break;  // 64
            case ED * CD * PD * PD:  wp  = (const float*)d_in[i]; break;  // 98304
            case ED:                 bp  = (const float*)d_in[i]; break;  // 128
        }
    }
    float* out = (float*)d_out;

    dim3 b1(64, 4, 1), g1(4, 56, BD);
    k_labels<<<g1, b1, 0, stream>>>(img, wsp, bsp);

    dim3 g2(SD, BD, 1);
    k_gather<<<g2, 256, 0, stream>>>(img);

    dim3 g3(SD, BD, 1);
    k_out<<<g3, 256, 0, stream>>>(wp, bp, out);
}

// Round 11
// 135.558 us; speedup vs baseline: 1.7978x; 1.7978x over previous
//
#include <hip/hip_runtime.h>

#define BD 8
#define SD 64
#define CD 3
#define HD 224
#define WD 224
#define ED 128
#define PD 16
#define HWD (HD*WD)
#define KD (CD*PD*PD)   /* 768 */
#define PRT 8           /* partitions per (b,c) for the hierarchical scatter */
#define CHK (HWD/PRT)   /* 6272 pixels per partition */

// All buffers fp32 (confirmed R6+ passes). Scratch in module globals; every
// byte below is fully overwritten each call -> no zero-init dispatch needed,
// and there are NO global atomics anywhere in the pipeline (R9 post-mortem:
// the 1.2M fp32 atomicAdd scatter cost 30MB of line-grain HBM RMW ~= 66us;
// R10 post-mortem: flat gather re-scanned labels 64x -> 133us latency-bound).
__device__ float              g_part[BD * CD * PRT * SD * 256];  // 12.6 MB partials
__device__ float              g_buf[BD * SD * KD];               // [b][lab][c][256]
__device__ int                g_labels[BD * HWD];
__device__ unsigned long long g_ppres[BD * PRT];                 // presence per (b,part)

// Kernel 1: 3x3 SAME conv -> argmax(64ch) -> labels store. R10-proven.
__global__ __launch_bounds__(256) void k_labels(
    const float* __restrict__ img,
    const float* __restrict__ wsp,
    const float* __restrict__ bsp)
{
    const int w = blockIdx.x * 64 + threadIdx.x;
    const int h = blockIdx.y * 4 + threadIdx.y;
    const int b = blockIdx.z;
    if (w >= WD) return;

    const float* ib = img + (size_t)b * CD * HWD;
    float pix[27];
    #pragma unroll
    for (int c = 0; c < 3; ++c)
        #pragma unroll
        for (int dh = 0; dh < 3; ++dh)
            #pragma unroll
            for (int dw = 0; dw < 3; ++dw) {
                int hh = h + dh - 1, ww = w + dw - 1;
                bool ok = (hh >= 0) & (hh < HD) & (ww >= 0) & (ww < WD);
                pix[(c * 3 + dh) * 3 + dw] = ok ? ib[c * HWD + hh * WD + ww] : 0.f;
            }

    float best = -INFINITY;
    int bi = 0;
    for (int s = 0; s < SD; ++s) {
        const float* wr = wsp + s * 27;        // wave-uniform -> s_load
        float acc = bsp[s];
        #pragma unroll
        for (int j = 0; j < 27; ++j) acc = fmaf(pix[j], wr[j], acc);
        if (acc > best) { best = acc; bi = s; }   // strict > = first max (jnp.argmax)
    }
    g_labels[b * HWD + h * WD + w] = bi;
}

// Kernel 2: hierarchical scatter. Block = (partition, channel, batch); owns a
// 6272-pixel chunk, accumulates into a 64KB LDS table [lab][cell] via LDS
// atomics (<=4-way conflicts), writes its partial table exclusively (coalesced).
// Presence mask per (b,part) from in-register OR + wave shfl-OR (c==0 blocks).
__global__ __launch_bounds__(256) void k_hist(const float* __restrict__ img)
{
    const int part = blockIdx.x, c = blockIdx.y, b = blockIdx.z;
    const int tid = threadIdx.x;

    __shared__ float acc[SD * 256];            // 64 KB
    __shared__ unsigned long long pm;
    #pragma unroll
    for (int k = 0; k < 16; ++k)
        ((float4*)acc)[k * 256 + tid] = make_float4(0.f, 0.f, 0.f, 0.f);
    if (tid == 0) pm = 0ull;
    __syncthreads();

    const int start = part * CHK;
    const int*   lb = g_labels + (size_t)b * HWD;
    const float* ic = img + ((size_t)b * CD + c) * HWD;

    unsigned long long m = 0ull;
    for (int p = start + tid; p < start + CHK; p += 256) {
        const int lab = lb[p];                 // coalesced, L2-resident
        const int h = p / WD, w = p - h * WD;
        const int cell = ((h & 15) << 4) | (w & 15);
        atomicAdd(&acc[lab * 256 + cell], ic[p]);
        m |= 1ull << lab;
    }
    #pragma unroll
    for (int d = 1; d < 64; d <<= 1) m |= __shfl_xor(m, d, 64);
    if ((tid & 63) == 0) atomicOr(&pm, m);
    __syncthreads();

    float4* dst = (float4*)(g_part + (((size_t)(b * CD + c)) * PRT + part) * (SD * 256));
    #pragma unroll
    for (int k = 0; k < 16; ++k)
        dst[k * 256 + tid] = ((float4*)acc)[k * 256 + tid];
    if (c == 0 && tid == 0) g_ppres[b * PRT + part] = pm;
}

// Kernel 3: merge the PRT partial tables -> g_buf[b][lab][c][256]. Coalesced.
__global__ __launch_bounds__(256) void k_merge()
{
    const int t = blockIdx.x * 256 + threadIdx.x;   // 98304 float4-slots
    const int cell4 = t & 63;
    int q = t >> 6;
    const int c = q % 3; q /= 3;
    const int lab = q & 63;
    const int b = q >> 6;

    const float4* src = (const float4*)g_part
        + ((size_t)(b * CD + c) * PRT) * 4096 + lab * 64 + cell4;
    float4 s = src[0];
    #pragma unroll
    for (int p2 = 1; p2 < PRT; ++p2) {
        float4 v = src[(size_t)p2 * 4096];
        s.x += v.x; s.y += v.y; s.z += v.z; s.w += v.w;
    }
    ((float4*)g_buf)[t] = s;
}

// Kernel 4: out[b,i,e] = bias[e] + (1/196)*dot(g_buf[b,uniq(b,i),:], wp[e,:]).
// uniq(b,i) = i-th set bit of the presence mask (OR of partition masks).
__global__ __launch_bounds__(256) void k_out(
    const float* __restrict__ wp,
    const float* __restrict__ bp,
    float* __restrict__ out)
{
    const int i = blockIdx.x;
    const int b = blockIdx.y;
    const int lane = threadIdx.x & 63;
    const int wv = threadIdx.x >> 6;

    unsigned long long m = 0ull;
    #pragma unroll
    for (int p2 = 0; p2 < PRT; ++p2) m |= g_ppres[b * PRT + p2];  // uniform -> s_load

    int l = 0;
    if (i < __popcll(m)) {
        unsigned long long mm = m;
        for (int t = 0; t < i; ++t) mm &= mm - 1;   // clear i lowest set bits
        l = __builtin_ctzll(mm);                    // i-th smallest label (sorted unique)
    }

    const float4* gr = (const float4*)(g_buf + (size_t)(b * SD + l) * KD);
    const float4 g0 = gr[lane], g1 = gr[lane + 64], g2 = gr[lane + 128];

    #pragma unroll 4
    for (int j = 0; j < 32; ++j) {
        const int e = wv * 32 + j;
        const float4* wr = (const float4*)(wp + (size_t)e * KD);
        float4 a0 = wr[lane], a1 = wr[lane + 64], a2 = wr[lane + 128];  // coalesced 1KB/wave
        float acc = g0.x * a0.x;
        acc = fmaf(g0.y, a0.y, acc); acc = fmaf(g0.z, a0.z, acc); acc = fmaf(g0.w, a0.w, acc);
        acc = fmaf(g1.x, a1.x, acc); acc = fmaf(g1.y, a1.y, acc);
        acc = fmaf(g1.z, a1.z, acc); acc = fmaf(g1.w, a1.w, acc);
        acc = fmaf(g2.x, a2.x, acc); acc = fmaf(g2.y, a2.y, acc);
        acc = fmaf(g2.z, a2.z, acc); acc = fmaf(g2.w, a2.w, acc);
        #pragma unroll
        for (int off = 32; off; off >>= 1) acc += __shfl_xor(acc, off, 64);
        if (lane == 0)
            out[(size_t)(b * SD + i) * ED + e] = bp[e] + acc * (1.f / 196.f);
    }
}

extern "C" void kernel_launch(void* const* d_in, const int* in_sizes, int n_in,
                              void* d_out, int out_size, void* d_ws, size_t ws_size,
                              hipStream_t stream) {
    const float *img = nullptr, *wsp = nullptr, *bsp = nullptr, *wp = nullptr, *bp = nullptr;
    for (int i = 0; i < n_in; ++i) {
        switch (in_sizes[i]) {
            case BD * CD * HWD:      img = (const float*)d_in[i]; break;  // 1204224
            case SD * CD * 9:        wsp = (const float*)d_in[i]; break;  // 1728
            case SD:                 bsp = (const float*)d_in[i]; break;  // 64
            case ED * CD * PD * PD:  wp  = (const float*)d_in[i]; break;  // 98304
            case ED:                 bp  = (const float*)d_in[i]; break;  // 128
        }
    }
    float* out = (float*)d_out;

    dim3 b1(64, 4, 1), g1(4, 56, BD);
    k_labels<<<g1, b1, 0, stream>>>(img, wsp, bsp);

    dim3 g2(PRT, CD, BD);
    k_hist<<<g2, 256, 0, stream>>>(img);

    k_merge<<<384, 256, 0, stream>>>();

    dim3 g4(SD, BD, 1);
    k_out<<<g4, 256, 0, stream>>>(wp, bp, out);
}